// Round 9
// baseline (59.744 us; speedup 1.0000x reference)
//
#include <hip/hip_runtime.h>
#include <math.h>

#define H_BINS 61
#define HB2 (H_BINS * H_BINS)       // 3721
#define SLOTS (3 * HB2)             // 11163
#define SLOTS_PAD 11164
#define NPIX 22500
#define NIMG 64
#define CH 9
#define QPC 625                     // quads per chunk
#define Q_PER_IMG 5625              // quads per image
#define NQ (NIMG * Q_PER_IMG)       // 360000 quads total
#define OUT_ELEMS (NIMG * SLOTS)
#define QPI (SLOTS_PAD / 4)

#define EPSF 2.2204e-16f
#define HALFW ((float)(6.4 / 61.0 / 2.0))

__device__ __forceinline__ float bin_center(int h) {
    const float delta = __fdiv_rn(__fsub_rn(3.0951f, -3.2f), 60.0f);
    return __fadd_rn(-3.2f, __fmul_rn((float)h, delta));
}

// Exact-predicate bin lookup, 2 candidates, branchless, array-free (R7/R8).
__device__ __forceinline__ int find_bin(float t) {
    const float inv_delta = 60.0f / 6.2951f;   // estimate only
    int k = (int)floorf(__fmul_rn(__fadd_rn(t, 3.2f), inv_delta));
    int best = -1;
    #pragma unroll
    for (int dh = 0; dh <= 1; ++dh) {
        int h = k + dh;
        bool in_rng = ((unsigned)h < (unsigned)H_BINS);
        bool hit = (fabsf(__fsub_rn(t, bin_center(h))) <= HALFW);
        best = (in_rng && hit) ? h : best;
    }
    return best;
}

// Encode one pixel: 3 pair-codes (bu*61+bv or 0xFFFF) + iy. Ops identical to
// all passing rounds: rn intrinsics, libm logf, exact f32 predicate.
#define ENC(r, g, bl, C0, C1, C2, IY)                                         \
    {                                                                         \
        float iy_ = __fsqrt_rn(__fadd_rn(                                     \
            __fadd_rn(__fmul_rn(r, r), __fmul_rn(g, g)), __fmul_rn(bl, bl))); \
        float l0 = logf(__fadd_rn(fabsf(r),  EPSF));                          \
        float l1 = logf(__fadd_rn(fabsf(g),  EPSF));                          \
        float l2 = logf(__fadd_rn(fabsf(bl), EPSF));                          \
        int bu0 = find_bin(__fsub_rn(l0, l1));                                \
        int bv0 = find_bin(__fsub_rn(l0, l2));                                \
        int bu1 = find_bin(__fsub_rn(l1, l0));                                \
        int bv1 = find_bin(__fsub_rn(l1, l2));                                \
        int bu2 = find_bin(__fsub_rn(l2, l0));                                \
        int bv2 = find_bin(__fsub_rn(l2, l1));                                \
        C0 = (bu0 >= 0 && bv0 >= 0) ? (unsigned short)(bu0 * H_BINS + bv0)    \
                                    : (unsigned short)0xFFFF;                 \
        C1 = (bu1 >= 0 && bv1 >= 0) ? (unsigned short)(bu1 * H_BINS + bv1)    \
                                    : (unsigned short)0xFFFF;                 \
        C2 = (bu2 >= 0 && bv2 >= 0) ? (unsigned short)(bu2 * H_BINS + bv2)    \
                                    : (unsigned short)0xFFFF;                 \
        IY = iy_;                                                             \
    }

// Pass 1: streaming compute, no LDS, full occupancy. All logf/find_bin here.
__global__ __launch_bounds__(256) void log_kernel(const float* __restrict__ X,
                                                  unsigned short* __restrict__ c0,
                                                  unsigned short* __restrict__ c1,
                                                  unsigned short* __restrict__ c2,
                                                  float* __restrict__ iyArr) {
    int q = blockIdx.x * 256 + threadIdx.x;
    if (q >= NQ) return;
    int b  = q / Q_PER_IMG;
    int qq = q - b * Q_PER_IMG;
    const float* base = X + (size_t)b * 3 * NPIX + 4 * qq;
    float4 r4 = *(const float4*)base;
    float4 g4 = *(const float4*)(base + NPIX);
    float4 b4 = *(const float4*)(base + 2 * NPIX);

    ushort4 o0, o1, o2; float4 oy;
    ENC(r4.x, g4.x, b4.x, o0.x, o1.x, o2.x, oy.x)
    ENC(r4.y, g4.y, b4.y, o0.y, o1.y, o2.y, oy.y)
    ENC(r4.z, g4.z, b4.z, o0.z, o1.z, o2.z, oy.z)
    ENC(r4.w, g4.w, b4.w, o0.w, o1.w, o2.w, oy.w)

    *(ushort4*)(c0 + 4 * (size_t)q) = o0;    // 8B coalesced
    *(ushort4*)(c1 + 4 * (size_t)q) = o1;
    *(ushort4*)(c2 + 4 * (size_t)q) = o2;
    *(float4*)(iyArr + 4 * (size_t)q) = oy;  // 16B coalesced
}

// Pass 2: pure LDS scatter — 3 dword loads + <=3 ds_add per pixel.
__global__ __launch_bounds__(640) void scatter_kernel(const unsigned short* __restrict__ c0,
                                                      const unsigned short* __restrict__ c1,
                                                      const unsigned short* __restrict__ c2,
                                                      const float* __restrict__ iyArr,
                                                      float* __restrict__ partials) {
    __shared__ float hflat[SLOTS_PAD];
    const int bid = blockIdx.x;
    const int b   = bid & 63;
    const int c   = bid >> 6;

    {
        float4* h4 = (float4*)hflat;
        float4 z = make_float4(0.f, 0.f, 0.f, 0.f);
        for (int i = threadIdx.x; i < SLOTS_PAD / 4; i += 640) h4[i] = z;
    }
    __syncthreads();

    if (threadIdx.x < QPC) {
        int q = b * Q_PER_IMG + c * QPC + threadIdx.x;
        ushort4 q0 = *(const ushort4*)(c0 + 4 * (size_t)q);
        ushort4 q1 = *(const ushort4*)(c1 + 4 * (size_t)q);
        ushort4 q2 = *(const ushort4*)(c2 + 4 * (size_t)q);
        float4  y  = *(const float4*)(iyArr + 4 * (size_t)q);
        #define SC(P, CODE, Y) \
            if ((CODE) != 0xFFFFu) unsafeAtomicAdd(&hflat[(P) * HB2 + (CODE)], (Y));
        SC(0, q0.x, y.x) SC(1, q1.x, y.x) SC(2, q2.x, y.x)
        SC(0, q0.y, y.y) SC(1, q1.y, y.y) SC(2, q2.y, y.y)
        SC(0, q0.z, y.z) SC(1, q1.z, y.z) SC(2, q2.z, y.z)
        SC(0, q0.w, y.w) SC(1, q1.w, y.w) SC(2, q2.w, y.w)
        #undef SC
    }
    __syncthreads();

    float4* dst = (float4*)(partials + (size_t)bid * SLOTS_PAD);
    const float4* src = (const float4*)hflat;
    for (int i = threadIdx.x; i < SLOTS_PAD / 4; i += 640) dst[i] = src[i];
}

// One block per image: sum 9 partials, sqrt*C/N, write out (R8, unchanged).
__global__ __launch_bounds__(1024) void reduce_kernel(const float* __restrict__ partials,
                                                      const float* __restrict__ C,
                                                      float* __restrict__ out) {
    const int b = blockIdx.x;
    float sc0 = __fdiv_rn(C[0], 22500.0f);
    float sc1 = __fdiv_rn(C[1], 22500.0f);
    float sc2 = __fdiv_rn(C[2], 22500.0f);
    const float* base0 = partials + (size_t)b * SLOTS_PAD;
    float* ob = out + (size_t)b * SLOTS;

    for (int t = threadIdx.x; t < QPI; t += 1024) {
        int j = t * 4;
        const float* base = base0 + j;
        float4 s = *(const float4*)base;
        #pragma unroll
        for (int c = 1; c < CH; ++c) {
            float4 v = *(const float4*)(base + (size_t)c * 64 * SLOTS_PAD);
            s.x = __fadd_rn(s.x, v.x); s.y = __fadd_rn(s.y, v.y);
            s.z = __fadd_rn(s.z, v.z); s.w = __fadd_rn(s.w, v.w);
        }
        #pragma unroll
        for (int k = 0; k < 4; ++k) {
            int jj = j + k;
            if (jj >= SLOTS) break;
            int ch = jj / HB2;
            float sv = (k == 0) ? s.x : (k == 1) ? s.y : (k == 2) ? s.z : s.w;
            float scale = (ch == 0) ? sc0 : (ch == 1) ? sc1 : sc2;
            ob[jj] = __fmul_rn(__fsqrt_rn(sv), scale);
        }
    }
}

// ---- tiny-ws fallback (not taken with 256MB ws) ----
#define DO_PAIR(P, IU, IV)                                                   \
    {                                                                        \
        int bu_ = find_bin(IU);                                              \
        int bv_ = find_bin(IV);                                              \
        if (bu_ >= 0 && bv_ >= 0)                                            \
            unsafeAtomicAdd(&hflat[(P) * HB2 + bu_ * H_BINS + bv_], iy);     \
    }
#define DO_PIXEL(r, g, bl)                                                   \
    {                                                                        \
        float iy = __fsqrt_rn(__fadd_rn(                                     \
            __fadd_rn(__fmul_rn(r, r), __fmul_rn(g, g)), __fmul_rn(bl, bl)));\
        float l0 = logf(__fadd_rn(fabsf(r),  EPSF));                         \
        float l1 = logf(__fadd_rn(fabsf(g),  EPSF));                         \
        float l2 = logf(__fadd_rn(fabsf(bl), EPSF));                         \
        float d01 = __fsub_rn(l0, l1);                                       \
        float d02 = __fsub_rn(l0, l2);                                       \
        float d12 = __fsub_rn(l1, l2);                                       \
        float d10 = __fsub_rn(l1, l0);                                       \
        float d20 = __fsub_rn(l2, l0);                                       \
        float d21 = __fsub_rn(l2, l1);                                       \
        DO_PAIR(0, d01, d02)                                                 \
        DO_PAIR(1, d10, d12)                                                 \
        DO_PAIR(2, d20, d21)                                                 \
    }
__global__ __launch_bounds__(256) void zero_kernel(float4* __restrict__ o, int n4) {
    int i = blockIdx.x * 256 + threadIdx.x;
    if (i < n4) o[i] = make_float4(0.f, 0.f, 0.f, 0.f);
}
__global__ __launch_bounds__(512) void hist_atomic(const float* __restrict__ X,
                                                   float* __restrict__ out) {
    __shared__ float hflat[SLOTS];
    const int chunk = blockIdx.x % 12;
    const int b     = blockIdx.x / 12;
    for (int i = threadIdx.x; i < SLOTS; i += 512) hflat[i] = 0.0f;
    __syncthreads();
    const float* Xb = X + (size_t)b * 3 * NPIX;
    const int ppc = NPIX / 12;
    for (int n = chunk * ppc + threadIdx.x; n < (chunk + 1) * ppc; n += 512) {
        float r = Xb[n], g = Xb[NPIX + n], bl = Xb[2 * NPIX + n];
        DO_PIXEL(r, g, bl)
    }
    __syncthreads();
    float* ob = out + (size_t)b * SLOTS;
    for (int i = threadIdx.x; i < SLOTS; i += 512) {
        float v = hflat[i];
        if (v != 0.0f) unsafeAtomicAdd(&ob[i], v);
    }
}
__global__ __launch_bounds__(256) void finalize_kernel(float* __restrict__ out,
                                                       const float* __restrict__ C) {
    int idx = blockIdx.x * 256 + threadIdx.x;
    if (idx >= OUT_ELEMS) return;
    int ch = (idx / HB2) % 3;
    float scale = __fdiv_rn(C[ch], 22500.0f);
    out[idx] = __fmul_rn(__fsqrt_rn(out[idx]), scale);
}

extern "C" void kernel_launch(void* const* d_in, const int* in_sizes, int n_in,
                              void* d_out, int out_size, void* d_ws, size_t ws_size,
                              hipStream_t stream) {
    const float* X = (const float*)d_in[0];
    const float* C = (const float*)d_in[1];
    float* out = (float*)d_out;
    char* ws = (char*)d_ws;

    // ws layout (all 256B-aligned): c0,c1,c2 (u16[4*NQ] each), iy (f32[4*NQ]),
    // partials (f32[576*SLOTS_PAD])
    const size_t SZ_C   = (size_t)2 * 4 * NQ;        // 2,880,000
    const size_t OFF_C0 = 0;
    const size_t OFF_C1 = SZ_C;
    const size_t OFF_C2 = 2 * SZ_C;
    const size_t OFF_IY = 3 * SZ_C;                  // 8,640,000
    const size_t SZ_IY  = (size_t)4 * 4 * NQ;        // 5,760,000
    const size_t OFF_PT = OFF_IY + SZ_IY;            // 14,400,000 (/256 ok)
    const size_t SZ_PT  = (size_t)NIMG * CH * SLOTS_PAD * 4;
    const size_t need   = OFF_PT + SZ_PT;            // ~40.1 MB

    if (ws_size >= need) {
        unsigned short* c0 = (unsigned short*)(ws + OFF_C0);
        unsigned short* c1 = (unsigned short*)(ws + OFF_C1);
        unsigned short* c2 = (unsigned short*)(ws + OFF_C2);
        float* iyArr    = (float*)(ws + OFF_IY);
        float* partials = (float*)(ws + OFF_PT);

        log_kernel<<<(NQ + 255) / 256, 256, 0, stream>>>(X, c0, c1, c2, iyArr);
        scatter_kernel<<<NIMG * CH, 640, 0, stream>>>(c0, c1, c2, iyArr, partials);
        reduce_kernel<<<NIMG, 1024, 0, stream>>>(partials, C, out);
    } else {
        int n4 = OUT_ELEMS / 4;
        zero_kernel<<<(n4 + 255) / 256, 256, 0, stream>>>((float4*)out, n4);
        hist_atomic<<<NIMG * 12, 512, 0, stream>>>(X, out);
        finalize_kernel<<<(OUT_ELEMS + 255) / 256, 256, 0, stream>>>(out, C);
    }
}